// Round 7
// baseline (450.841 us; speedup 1.0000x reference)
//
#include <hip/hip_runtime.h>
#include <hip/hip_bf16.h>
#include <math.h>

#define NUM_HEADS 6
#define DH 64
#define NSEQ 1024
#define DMODEL 384
#define BBATCH 8
#define WN 147456

typedef __attribute__((ext_vector_type(8))) short short8;
typedef __attribute__((ext_vector_type(4))) short s4v;
typedef __attribute__((ext_vector_type(4))) float floatx4;

static __device__ __forceinline__ short f2bf(float x) {
  union { float f; unsigned u; } un; un.f = x;
  unsigned r = un.u + 0x7fffu + ((un.u >> 16) & 1u);
  return (short)(r >> 16);
}
static __device__ __forceinline__ float bf2f(short s) {
  union { float f; unsigned u; } un;
  un.u = ((unsigned)(unsigned short)s) << 16;
  return un.f;
}

// ---------------- prep: x -> bf16, W -> bf16 hi/lo ----------------
__global__ __launch_bounds__(256) void prep_split(
    const float* __restrict__ x, const float* __restrict__ Wq,
    const float* __restrict__ Wk, const float* __restrict__ Wv,
    const float* __restrict__ Wp, short* __restrict__ xh,
    short* __restrict__ WH, short* __restrict__ WL) {
  const int idx = blockIdx.x * 256 + threadIdx.x;
  if (idx < 786432) {
    float4 v = ((const float4*)x)[idx];
    s4v h;
    h[0] = f2bf(v.x); h[1] = f2bf(v.y); h[2] = f2bf(v.z); h[3] = f2bf(v.w);
    ((s4v*)xh)[idx] = h;
  } else {
    int t = idx - 786432;
    int w = t / 36864;
    int rr = t - w * 36864;
    const float* W = (w == 0) ? Wq : (w == 1) ? Wk : (w == 2) ? Wv : Wp;
    float4 v = ((const float4*)W)[rr];
    s4v h, l;
    h[0] = f2bf(v.x); l[0] = f2bf(v.x - bf2f(h[0]));
    h[1] = f2bf(v.y); l[1] = f2bf(v.y - bf2f(h[1]));
    h[2] = f2bf(v.z); l[2] = f2bf(v.z - bf2f(h[2]));
    h[3] = f2bf(v.w); l[3] = f2bf(v.w - bf2f(h[3]));
    ((s4v*)(WH + (size_t)w * WN))[rr] = h;
    ((s4v*)(WL + (size_t)w * WN))[rr] = l;
  }
}

// ---------------- MFMA NT GEMM: C = A @ W^T, 2-pass, double-buffered ----------------
// W tiles (hi+lo, 8KB each) double-buffered in LDS via global_load_lds; one
// barrier per k-iter at loop top, then DMA(k+1) + A-reg prefetch(k+1), then
// compute(k) overlapping the in-flight DMA (attn_tile-proven pattern).
template <int MODE>
__global__ __launch_bounds__(256) void gemm_mfma(
    const short* __restrict__ Abf, const short* __restrict__ WH,
    const short* __restrict__ WL, const float* __restrict__ lam_ptr,
    short* __restrict__ qs, short* __restrict__ ks, short* __restrict__ vt,
    float* __restrict__ outp) {
  __shared__ short sBh[2][4096], sBl[2][4096];

  const int tid = threadIdx.x;
  const int wave = tid >> 6;
  const int lane = tid & 63;
  const int quad = lane >> 4;
  const int l16 = lane & 15;

  const int bm = blockIdx.x * 128;
  const int bn = blockIdx.y * 128;
  const int z = (MODE == 0) ? blockIdx.z : 3;

  float cs = 1.0f;
  if (MODE == 0 && z == 0) cs = 0.125f / (1.0f + __expf(-lam_ptr[0]));

  // staging: waves 0,1 -> hi; waves 2,3 -> lo; 4 x 16B DMA per thread per iter
  const short* __restrict__ Wsel = ((wave < 2) ? WH : WL) + (size_t)z * WN;
  short* sBbase = (wave < 2) ? &sBh[0][0] : &sBl[0][0];
  const int Gb = (wave & 1) * 256;
  const short* srcp[4];
  int dsto[4];
#pragma unroll
  for (int i = 0; i < 4; ++i) {
    const int G = Gb + i * 64 + lane;
    const int row = G >> 2;
    const int g = (G & 3) ^ ((G >> 3) & 3);
    srcp[i] = Wsel + (size_t)(bn + row) * DMODEL + g * 8;
    dsto[i] = (Gb + i * 64) * 8;
  }

  const short* aptr[2];
#pragma unroll
  for (int mt = 0; mt < 2; ++mt)
    aptr[mt] = Abf + (size_t)(bm + wave * 32 + mt * 16 + l16) * DMODEL + quad * 8;

  floatx4 acc[2][8];
#pragma unroll
  for (int i = 0; i < 2; ++i)
#pragma unroll
    for (int j = 0; j < 8; ++j) acc[i][j] = (floatx4){0.f, 0.f, 0.f, 0.f};

  // prologue: DMA k-tile 0 -> buf 0; preload A-tile 0
#pragma unroll
  for (int i = 0; i < 4; ++i)
    __builtin_amdgcn_global_load_lds(
        (const __attribute__((address_space(1))) unsigned*)srcp[i],
        (__attribute__((address_space(3))) unsigned*)(sBbase + dsto[i]), 16, 0, 0);
  short8 ar[2][2];
  ar[0][0] = *(const short8*)aptr[0];
  ar[0][1] = *(const short8*)aptr[1];

  for (int it = 0; it < 12; ++it) {
    const int cur = it & 1, nxt = cur ^ 1;
    __syncthreads();  // DMA(it) landed; buf[nxt] readers (iter it-1) done
    if (it + 1 < 12) {
      const int ko = (it + 1) * 32;
#pragma unroll
      for (int i = 0; i < 4; ++i)
        __builtin_amdgcn_global_load_lds(
            (const __attribute__((address_space(1))) unsigned*)(srcp[i] + ko),
            (__attribute__((address_space(3))) unsigned*)(sBbase + nxt * 4096 + dsto[i]),
            16, 0, 0);
      ar[nxt][0] = *(const short8*)(aptr[0] + ko);
      ar[nxt][1] = *(const short8*)(aptr[1] + ko);
    }
#pragma unroll
    for (int nt = 0; nt < 8; ++nt) {
      const int row = nt * 16 + l16;
      const int off = row * 32 + ((quad ^ ((row >> 1) & 3)) << 3);
      short8 bfh = *(const short8*)&sBh[cur][off];
      short8 bfl = *(const short8*)&sBl[cur][off];
      acc[0][nt] = __builtin_amdgcn_mfma_f32_16x16x32_bf16(ar[cur][0], bfh, acc[0][nt], 0, 0, 0);
      acc[0][nt] = __builtin_amdgcn_mfma_f32_16x16x32_bf16(ar[cur][0], bfl, acc[0][nt], 0, 0, 0);
      acc[1][nt] = __builtin_amdgcn_mfma_f32_16x16x32_bf16(ar[cur][1], bfh, acc[1][nt], 0, 0, 0);
      acc[1][nt] = __builtin_amdgcn_mfma_f32_16x16x32_bf16(ar[cur][1], bfl, acc[1][nt], 0, 0, 0);
    }
  }

#pragma unroll
  for (int mt = 0; mt < 2; ++mt) {
    const int m0 = bm + wave * 32 + mt * 16 + quad * 4;
    const int b = m0 >> 10;
    const int n0 = m0 & (NSEQ - 1);
#pragma unroll
    for (int nt = 0; nt < 8; ++nt) {
      const int c = bn + nt * 16 + l16;
      if constexpr (MODE == 0) {
        const int head = c >> 6;
        const int d = c & 63;
        if (z == 2) {
          s4v sv;
          sv[0] = f2bf(acc[mt][nt][0]); sv[1] = f2bf(acc[mt][nt][1]);
          sv[2] = f2bf(acc[mt][nt][2]); sv[3] = f2bf(acc[mt][nt][3]);
          *(s4v*)&vt[((size_t)(b * NUM_HEADS + head) * DH + d) * NSEQ + n0] = sv;
        } else {
          short* tgt = z ? ks : qs;
#pragma unroll
          for (int r = 0; r < 4; ++r)
            tgt[((size_t)(b * NUM_HEADS + head) * NSEQ + n0 + r) * DH + d] =
                f2bf(acc[mt][nt][r] * cs);
        }
      } else {
#pragma unroll
        for (int r = 0; r < 4; ++r)
          outp[(size_t)(m0 + r) * DMODEL + c] = acc[mt][nt][r];
      }
    }
  }
}

// ---------------- LDS-shared tiled attention (unchanged from R5) ----------------
__global__ __launch_bounds__(512) void attn_tile(
    const short* __restrict__ qs, const short* __restrict__ ks,
    const short* __restrict__ vt, short* __restrict__ aoh,
    const float* __restrict__ lam_ptr, const float* __restrict__ lsig_ptr) {
  __shared__ short sK[2][4096];
  __shared__ short sVT[2][4096];
  __shared__ short sP[8 * 1024];

  const int tid = threadIdx.x;
  const int wave = tid >> 6;
  const int lane = tid & 63;
  const int quad = lane >> 4;
  const int l16 = lane & 15;
  const int l16a7 = l16 & 7;

  const int bh = blockIdx.y;
  const int qbase = blockIdx.x << 7;

  const short* qb = qs + (size_t)bh * NSEQ * DH;
  const short* kb = ks + (size_t)bh * NSEQ * DH;
  const short* vb = vt + (size_t)bh * DH * NSEQ;

  const float lam = 1.0f / (1.0f + __expf(-lam_ptr[0]));
  const float sg = log1pf(__expf(lsig_ptr[0])) + 1e-6f;
  const float ninv2s2 = -1.0f / (2.0f * sg * sg);
  const float pscale = 1.0f - lam;

  const int la31 = lane & 31;
  const float Etv = __expf(ninv2s2 * (float)(la31 * la31));
  float Exh[2][4];
#pragma unroll
  for (int mp = 0; mp < 2; ++mp)
#pragma unroll
    for (int r = 0; r < 4; ++r) {
      const int dx = (wave & 1) * 16 + l16 - mp * 16 - quad * 4 - r;
      const int idx = dx < 0 ? -dx : dx;
      Exh[mp][r] = __int_as_float(
          __builtin_amdgcn_ds_bpermute(idx << 2, __float_as_int(Etv)));
    }
  const int qy = (qbase >> 5) + (wave >> 1);

  const int qrow = qbase + wave * 16 + l16;
  short8 aqf0 = *(const short8*)&qb[(size_t)qrow * DH + quad * 8];
  short8 aqf1 = *(const short8*)&qb[(size_t)qrow * DH + 32 + quad * 8];

  const int Gr = tid >> 3;
  const int Gg = (tid & 7) ^ (Gr & 7);
  const short* srcK = kb + (size_t)Gr * DH + Gg * 8;
  const short* srcV = vb + (size_t)Gr * NSEQ + Gg * 8;
  const int dstoff = wave * 512;

  floatx4 oacc[4];
#pragma unroll
  for (int t = 0; t < 4; ++t) oacc[t] = (floatx4){0.f, 0.f, 0.f, 0.f};
  float plsum = 0.f;

  __builtin_amdgcn_global_load_lds(
      (const __attribute__((address_space(1))) unsigned*)srcK,
      (__attribute__((address_space(3))) unsigned*)&sK[0][dstoff], 16, 0, 0);
  __builtin_amdgcn_global_load_lds(
      (const __attribute__((address_space(1))) unsigned*)srcV,
      (__attribute__((address_space(3))) unsigned*)&sVT[0][dstoff], 16, 0, 0);

  for (int ch = 0; ch < 16; ++ch) {
    __syncthreads();
    if (ch + 1 < 16) {
      const int nb = (ch + 1) & 1;
      __builtin_amdgcn_global_load_lds(
          (const __attribute__((address_space(1))) unsigned*)(srcK + (ch + 1) * 4096),
          (__attribute__((address_space(3))) unsigned*)&sK[nb][dstoff], 16, 0, 0);
      __builtin_amdgcn_global_load_lds(
          (const __attribute__((address_space(1))) unsigned*)(srcV + (ch + 1) * 64),
          (__attribute__((address_space(3))) unsigned*)&sVT[nb][dstoff], 16, 0, 0);
    }
    const int buf = ch & 1;

    short8 kf[4][2];
#pragma unroll
    for (int mt = 0; mt < 4; ++mt) {
      const int row = mt * 16 + l16;
#pragma unroll
      for (int h = 0; h < 2; ++h) {
        const int g = h * 4 + quad;
        kf[mt][h] = *(const short8*)&sK[buf][row * 64 + ((g ^ (row & 7)) << 3)];
      }
    }

    floatx4 S[4];
#pragma unroll
    for (int mt = 0; mt < 4; ++mt) {
      floatx4 c = {0.f, 0.f, 0.f, 0.f};
      c = __builtin_amdgcn_mfma_f32_16x16x32_bf16(kf[mt][0], aqf0, c, 0, 0, 0);
      c = __builtin_amdgcn_mfma_f32_16x16x32_bf16(kf[mt][1], aqf1, c, 0, 0, 0);
      S[mt] = c;
    }

    const float dy0 = (float)(qy - 2 * ch);
    const float dy1 = dy0 - 1.0f;
    float ey[2];
    ey[0] = pscale * __expf(ninv2s2 * dy0 * dy0);
    ey[1] = pscale * __expf(ninv2s2 * dy1 * dy1);

#pragma unroll
    for (int mt = 0; mt < 4; ++mt) {
      s4v pk;
#pragma unroll
      for (int r = 0; r < 4; ++r) {
        const float p = __expf(fmaf(ey[mt >> 1], Exh[mt & 1][r], S[mt][r]));
        plsum += p;
        pk[r] = f2bf(p);
      }
      const int gg = mt * 4 + quad;
      const int off = wave * 1024 + l16 * 64 + (((gg >> 1) ^ l16a7) << 3) + ((gg & 1) << 2);
      *(s4v*)&sP[off] = pk;
    }

    short8 pA0 = *(const short8*)&sP[wave * 1024 + l16 * 64 + ((quad ^ l16a7) << 3)];
    short8 pA1 = *(const short8*)&sP[wave * 1024 + l16 * 64 + (((4 + quad) ^ l16a7) << 3)];

#pragma unroll
    for (int dt = 0; dt < 4; ++dt) {
      const int row = dt * 16 + l16;
      short8 vf0 = *(const short8*)&sVT[buf][row * 64 + ((quad ^ (row & 7)) << 3)];
      short8 vf1 = *(const short8*)&sVT[buf][row * 64 + (((4 + quad) ^ (row & 7)) << 3)];
      oacc[dt] = __builtin_amdgcn_mfma_f32_16x16x32_bf16(pA0, vf0, oacc[dt], 0, 0, 0);
      oacc[dt] = __builtin_amdgcn_mfma_f32_16x16x32_bf16(pA1, vf1, oacc[dt], 0, 0, 0);
    }
  }

  plsum += __shfl_xor(plsum, 16, 64);
  plsum += __shfl_xor(plsum, 32, 64);
  const float inv = 1.0f / plsum;
  float invr[4];
#pragma unroll
  for (int rr = 0; rr < 4; ++rr)
    invr[rr] = __int_as_float(
        __builtin_amdgcn_ds_bpermute((quad * 4 + rr) << 2, __float_as_int(inv)));

  const int b = bh / NUM_HEADS, head = bh % NUM_HEADS;
#pragma unroll
  for (int dt = 0; dt < 4; ++dt)
#pragma unroll
    for (int rr = 0; rr < 4; ++rr)
      aoh[(size_t)(b * NSEQ + qbase + wave * 16 + quad * 4 + rr) * DMODEL +
          head * DH + dt * 16 + l16] = f2bf(oacc[dt][rr] * invr[rr]);
}

extern "C" void kernel_launch(void* const* d_in, const int* in_sizes, int n_in,
                              void* d_out, int out_size, void* d_ws, size_t ws_size,
                              hipStream_t stream) {
  const float* x    = (const float*)d_in[0];
  const float* Wq   = (const float*)d_in[1];
  const float* Wk   = (const float*)d_in[2];
  const float* Wv   = (const float*)d_in[3];
  const float* Wp   = (const float*)d_in[4];
  const float* lamp = (const float*)d_in[5];
  const float* lsig = (const float*)d_in[6];
  float* out = (float*)d_out;

  char* ws = (char*)d_ws;
  const size_t NE = (size_t)BBATCH * NSEQ * DMODEL;  // 3,145,728
  short* xh = (short*)ws;            // later reused as attention output (bf16)
  short* WH = xh + NE;
  short* WL = WH + 4 * (size_t)WN;
  short* qs = WL + 4 * (size_t)WN;
  short* ks = qs + NE;
  short* vt = ks + NE;
  short* aoh = xh;                   // alias: x no longer needed after QKV

  prep_split<<<3648, 256, 0, stream>>>(x, Wq, Wk, Wv, Wp, xh, WH, WL);

  dim3 gq(64, 3, 3);
  gemm_mfma<0><<<gq, 256, 0, stream>>>(xh, WH, WL, lamp, qs, ks, vt, nullptr);

  attn_tile<<<dim3(8, 48), 512, 0, stream>>>(qs, ks, vt, aoh, lamp, lsig);

  dim3 gp(64, 3);
  gemm_mfma<1><<<gp, 256, 0, stream>>>(aoh, WH, WL, lamp, nullptr, nullptr, nullptr, out);
}

// Round 8
// 183.973 us; speedup vs baseline: 2.4506x; 2.4506x over previous
//
#include <hip/hip_runtime.h>
#include <hip/hip_bf16.h>
#include <math.h>

#define NUM_HEADS 6
#define DH 64
#define NSEQ 1024
#define DMODEL 384
#define BBATCH 8
#define WN 147456

typedef __attribute__((ext_vector_type(8))) short short8;
typedef __attribute__((ext_vector_type(4))) short s4v;
typedef __attribute__((ext_vector_type(4))) float floatx4;

static __device__ __forceinline__ short f2bf(float x) {
  union { float f; unsigned u; } un; un.f = x;
  unsigned r = un.u + 0x7fffu + ((un.u >> 16) & 1u);
  return (short)(r >> 16);
}
static __device__ __forceinline__ float bf2f(short s) {
  union { float f; unsigned u; } un;
  un.u = ((unsigned)(unsigned short)s) << 16;
  return un.f;
}

// ---------------- prep: x -> bf16, W -> bf16 hi/lo ----------------
__global__ __launch_bounds__(256) void prep_split(
    const float* __restrict__ x, const float* __restrict__ Wq,
    const float* __restrict__ Wk, const float* __restrict__ Wv,
    const float* __restrict__ Wp, short* __restrict__ xh,
    short* __restrict__ WH, short* __restrict__ WL) {
  const int idx = blockIdx.x * 256 + threadIdx.x;
  if (idx < 786432) {
    float4 v = ((const float4*)x)[idx];
    s4v h;
    h[0] = f2bf(v.x); h[1] = f2bf(v.y); h[2] = f2bf(v.z); h[3] = f2bf(v.w);
    ((s4v*)xh)[idx] = h;
  } else {
    int t = idx - 786432;
    int w = t / 36864;
    int rr = t - w * 36864;
    const float* W = (w == 0) ? Wq : (w == 1) ? Wk : (w == 2) ? Wv : Wp;
    float4 v = ((const float4*)W)[rr];
    s4v h, l;
    h[0] = f2bf(v.x); l[0] = f2bf(v.x - bf2f(h[0]));
    h[1] = f2bf(v.y); l[1] = f2bf(v.y - bf2f(h[1]));
    h[2] = f2bf(v.z); l[2] = f2bf(v.z - bf2f(h[2]));
    h[3] = f2bf(v.w); l[3] = f2bf(v.w - bf2f(h[3]));
    ((s4v*)(WH + (size_t)w * WN))[rr] = h;
    ((s4v*)(WL + (size_t)w * WN))[rr] = l;
  }
}

// ---------------- MFMA NT GEMM: C = A @ W^T, 2-pass, double-buffered ----------------
// FULLY UNROLLED pipeline: under #pragma unroll, cur/nxt are compile-time so
// ar[]/buffer indices stay in registers (un-unrolled version spilled ar[] to
// scratch -> 257us/dispatch, work-independent). One barrier per k-iter; DMA(k+1)
// + A-prefetch(k+1) issued right after it, in flight across compute(k).
template <int MODE>
__global__ __launch_bounds__(256) void gemm_mfma(
    const short* __restrict__ Abf, const short* __restrict__ WH,
    const short* __restrict__ WL, const float* __restrict__ lam_ptr,
    short* __restrict__ qs, short* __restrict__ ks, short* __restrict__ vt,
    float* __restrict__ outp) {
  __shared__ short sBh[2][4096], sBl[2][4096];

  const int tid = threadIdx.x;
  const int wave = tid >> 6;
  const int lane = tid & 63;
  const int quad = lane >> 4;
  const int l16 = lane & 15;

  const int bm = blockIdx.x * 128;
  const int bn = blockIdx.y * 128;
  const int z = (MODE == 0) ? blockIdx.z : 3;

  float cs = 1.0f;
  if (MODE == 0 && z == 0) cs = 0.125f / (1.0f + __expf(-lam_ptr[0]));

  // staging: waves 0,1 -> hi; waves 2,3 -> lo; 4 x 16B DMA per thread per iter
  const short* __restrict__ Wsel = ((wave < 2) ? WH : WL) + (size_t)z * WN;
  short* sBbase = (wave < 2) ? &sBh[0][0] : &sBl[0][0];
  const int Gb = (wave & 1) * 256;
  const short* srcp[4];
  int dsto[4];
#pragma unroll
  for (int i = 0; i < 4; ++i) {
    const int G = Gb + i * 64 + lane;
    const int row = G >> 2;
    const int g = (G & 3) ^ ((G >> 3) & 3);
    srcp[i] = Wsel + (size_t)(bn + row) * DMODEL + g * 8;
    dsto[i] = (Gb + i * 64) * 8;
  }

  const short* aptr[2];
#pragma unroll
  for (int mt = 0; mt < 2; ++mt)
    aptr[mt] = Abf + (size_t)(bm + wave * 32 + mt * 16 + l16) * DMODEL + quad * 8;

  floatx4 acc[2][8];
#pragma unroll
  for (int i = 0; i < 2; ++i)
#pragma unroll
    for (int j = 0; j < 8; ++j) acc[i][j] = (floatx4){0.f, 0.f, 0.f, 0.f};

  // prologue: DMA k-tile 0 -> buf 0; preload A-tile 0
#pragma unroll
  for (int i = 0; i < 4; ++i)
    __builtin_amdgcn_global_load_lds(
        (const __attribute__((address_space(1))) unsigned*)srcp[i],
        (__attribute__((address_space(3))) unsigned*)(sBbase + dsto[i]), 16, 0, 0);
  short8 ar[2][2];
  ar[0][0] = *(const short8*)aptr[0];
  ar[0][1] = *(const short8*)aptr[1];

#pragma unroll
  for (int it = 0; it < 12; ++it) {
    const int cur = it & 1, nxt = cur ^ 1;
    __syncthreads();  // DMA(it) landed; buf[nxt] readers (iter it-1) done
    if (it + 1 < 12) {
      const int ko = (it + 1) * 32;
#pragma unroll
      for (int i = 0; i < 4; ++i)
        __builtin_amdgcn_global_load_lds(
            (const __attribute__((address_space(1))) unsigned*)(srcp[i] + ko),
            (__attribute__((address_space(3))) unsigned*)(sBbase + nxt * 4096 + dsto[i]),
            16, 0, 0);
      ar[nxt][0] = *(const short8*)(aptr[0] + ko);
      ar[nxt][1] = *(const short8*)(aptr[1] + ko);
    }
#pragma unroll
    for (int nt = 0; nt < 8; ++nt) {
      const int row = nt * 16 + l16;
      const int off = row * 32 + ((quad ^ ((row >> 1) & 3)) << 3);
      short8 bfh = *(const short8*)&sBh[cur][off];
      short8 bfl = *(const short8*)&sBl[cur][off];
      acc[0][nt] = __builtin_amdgcn_mfma_f32_16x16x32_bf16(ar[cur][0], bfh, acc[0][nt], 0, 0, 0);
      acc[0][nt] = __builtin_amdgcn_mfma_f32_16x16x32_bf16(ar[cur][0], bfl, acc[0][nt], 0, 0, 0);
      acc[1][nt] = __builtin_amdgcn_mfma_f32_16x16x32_bf16(ar[cur][1], bfh, acc[1][nt], 0, 0, 0);
      acc[1][nt] = __builtin_amdgcn_mfma_f32_16x16x32_bf16(ar[cur][1], bfl, acc[1][nt], 0, 0, 0);
    }
  }

#pragma unroll
  for (int mt = 0; mt < 2; ++mt) {
    const int m0 = bm + wave * 32 + mt * 16 + quad * 4;
    const int b = m0 >> 10;
    const int n0 = m0 & (NSEQ - 1);
#pragma unroll
    for (int nt = 0; nt < 8; ++nt) {
      const int c = bn + nt * 16 + l16;
      if constexpr (MODE == 0) {
        const int head = c >> 6;
        const int d = c & 63;
        if (z == 2) {
          s4v sv;
          sv[0] = f2bf(acc[mt][nt][0]); sv[1] = f2bf(acc[mt][nt][1]);
          sv[2] = f2bf(acc[mt][nt][2]); sv[3] = f2bf(acc[mt][nt][3]);
          *(s4v*)&vt[((size_t)(b * NUM_HEADS + head) * DH + d) * NSEQ + n0] = sv;
        } else {
          short* tgt = z ? ks : qs;
#pragma unroll
          for (int r = 0; r < 4; ++r)
            tgt[((size_t)(b * NUM_HEADS + head) * NSEQ + n0 + r) * DH + d] =
                f2bf(acc[mt][nt][r] * cs);
        }
      } else {
#pragma unroll
        for (int r = 0; r < 4; ++r)
          outp[(size_t)(m0 + r) * DMODEL + c] = acc[mt][nt][r];
      }
    }
  }
}

// ---------------- LDS-shared tiled attention (unchanged from R5) ----------------
__global__ __launch_bounds__(512) void attn_tile(
    const short* __restrict__ qs, const short* __restrict__ ks,
    const short* __restrict__ vt, short* __restrict__ aoh,
    const float* __restrict__ lam_ptr, const float* __restrict__ lsig_ptr) {
  __shared__ short sK[2][4096];
  __shared__ short sVT[2][4096];
  __shared__ short sP[8 * 1024];

  const int tid = threadIdx.x;
  const int wave = tid >> 6;
  const int lane = tid & 63;
  const int quad = lane >> 4;
  const int l16 = lane & 15;
  const int l16a7 = l16 & 7;

  const int bh = blockIdx.y;
  const int qbase = blockIdx.x << 7;

  const short* qb = qs + (size_t)bh * NSEQ * DH;
  const short* kb = ks + (size_t)bh * NSEQ * DH;
  const short* vb = vt + (size_t)bh * DH * NSEQ;

  const float lam = 1.0f / (1.0f + __expf(-lam_ptr[0]));
  const float sg = log1pf(__expf(lsig_ptr[0])) + 1e-6f;
  const float ninv2s2 = -1.0f / (2.0f * sg * sg);
  const float pscale = 1.0f - lam;

  const int la31 = lane & 31;
  const float Etv = __expf(ninv2s2 * (float)(la31 * la31));
  float Exh[2][4];
#pragma unroll
  for (int mp = 0; mp < 2; ++mp)
#pragma unroll
    for (int r = 0; r < 4; ++r) {
      const int dx = (wave & 1) * 16 + l16 - mp * 16 - quad * 4 - r;
      const int idx = dx < 0 ? -dx : dx;
      Exh[mp][r] = __int_as_float(
          __builtin_amdgcn_ds_bpermute(idx << 2, __float_as_int(Etv)));
    }
  const int qy = (qbase >> 5) + (wave >> 1);

  const int qrow = qbase + wave * 16 + l16;
  short8 aqf0 = *(const short8*)&qb[(size_t)qrow * DH + quad * 8];
  short8 aqf1 = *(const short8*)&qb[(size_t)qrow * DH + 32 + quad * 8];

  const int Gr = tid >> 3;
  const int Gg = (tid & 7) ^ (Gr & 7);
  const short* srcK = kb + (size_t)Gr * DH + Gg * 8;
  const short* srcV = vb + (size_t)Gr * NSEQ + Gg * 8;
  const int dstoff = wave * 512;

  floatx4 oacc[4];
#pragma unroll
  for (int t = 0; t < 4; ++t) oacc[t] = (floatx4){0.f, 0.f, 0.f, 0.f};
  float plsum = 0.f;

  __builtin_amdgcn_global_load_lds(
      (const __attribute__((address_space(1))) unsigned*)srcK,
      (__attribute__((address_space(3))) unsigned*)&sK[0][dstoff], 16, 0, 0);
  __builtin_amdgcn_global_load_lds(
      (const __attribute__((address_space(1))) unsigned*)srcV,
      (__attribute__((address_space(3))) unsigned*)&sVT[0][dstoff], 16, 0, 0);

#pragma unroll
  for (int ch = 0; ch < 16; ++ch) {
    __syncthreads();
    if (ch + 1 < 16) {
      const int nb = (ch + 1) & 1;
      __builtin_amdgcn_global_load_lds(
          (const __attribute__((address_space(1))) unsigned*)(srcK + (ch + 1) * 4096),
          (__attribute__((address_space(3))) unsigned*)&sK[nb][dstoff], 16, 0, 0);
      __builtin_amdgcn_global_load_lds(
          (const __attribute__((address_space(1))) unsigned*)(srcV + (ch + 1) * 64),
          (__attribute__((address_space(3))) unsigned*)&sVT[nb][dstoff], 16, 0, 0);
    }
    const int buf = ch & 1;

    short8 kf[4][2];
#pragma unroll
    for (int mt = 0; mt < 4; ++mt) {
      const int row = mt * 16 + l16;
#pragma unroll
      for (int h = 0; h < 2; ++h) {
        const int g = h * 4 + quad;
        kf[mt][h] = *(const short8*)&sK[buf][row * 64 + ((g ^ (row & 7)) << 3)];
      }
    }

    floatx4 S[4];
#pragma unroll
    for (int mt = 0; mt < 4; ++mt) {
      floatx4 c = {0.f, 0.f, 0.f, 0.f};
      c = __builtin_amdgcn_mfma_f32_16x16x32_bf16(kf[mt][0], aqf0, c, 0, 0, 0);
      c = __builtin_amdgcn_mfma_f32_16x16x32_bf16(kf[mt][1], aqf1, c, 0, 0, 0);
      S[mt] = c;
    }

    const float dy0 = (float)(qy - 2 * ch);
    const float dy1 = dy0 - 1.0f;
    float ey[2];
    ey[0] = pscale * __expf(ninv2s2 * dy0 * dy0);
    ey[1] = pscale * __expf(ninv2s2 * dy1 * dy1);

#pragma unroll
    for (int mt = 0; mt < 4; ++mt) {
      s4v pk;
#pragma unroll
      for (int r = 0; r < 4; ++r) {
        const float p = __expf(fmaf(ey[mt >> 1], Exh[mt & 1][r], S[mt][r]));
        plsum += p;
        pk[r] = f2bf(p);
      }
      const int gg = mt * 4 + quad;
      const int off = wave * 1024 + l16 * 64 + (((gg >> 1) ^ l16a7) << 3) + ((gg & 1) << 2);
      *(s4v*)&sP[off] = pk;
    }

    short8 pA0 = *(const short8*)&sP[wave * 1024 + l16 * 64 + ((quad ^ l16a7) << 3)];
    short8 pA1 = *(const short8*)&sP[wave * 1024 + l16 * 64 + (((4 + quad) ^ l16a7) << 3)];

#pragma unroll
    for (int dt = 0; dt < 4; ++dt) {
      const int row = dt * 16 + l16;
      short8 vf0 = *(const short8*)&sVT[buf][row * 64 + ((quad ^ (row & 7)) << 3)];
      short8 vf1 = *(const short8*)&sVT[buf][row * 64 + (((4 + quad) ^ (row & 7)) << 3)];
      oacc[dt] = __builtin_amdgcn_mfma_f32_16x16x32_bf16(pA0, vf0, oacc[dt], 0, 0, 0);
      oacc[dt] = __builtin_amdgcn_mfma_f32_16x16x32_bf16(pA1, vf1, oacc[dt], 0, 0, 0);
    }
  }

  plsum += __shfl_xor(plsum, 16, 64);
  plsum += __shfl_xor(plsum, 32, 64);
  const float inv = 1.0f / plsum;
  float invr[4];
#pragma unroll
  for (int rr = 0; rr < 4; ++rr)
    invr[rr] = __int_as_float(
        __builtin_amdgcn_ds_bpermute((quad * 4 + rr) << 2, __float_as_int(inv)));

  const int b = bh / NUM_HEADS, head = bh % NUM_HEADS;
#pragma unroll
  for (int dt = 0; dt < 4; ++dt)
#pragma unroll
    for (int rr = 0; rr < 4; ++rr)
      aoh[(size_t)(b * NSEQ + qbase + wave * 16 + quad * 4 + rr) * DMODEL +
          head * DH + dt * 16 + l16] = f2bf(oacc[dt][rr] * invr[rr]);
}

extern "C" void kernel_launch(void* const* d_in, const int* in_sizes, int n_in,
                              void* d_out, int out_size, void* d_ws, size_t ws_size,
                              hipStream_t stream) {
  const float* x    = (const float*)d_in[0];
  const float* Wq   = (const float*)d_in[1];
  const float* Wk   = (const float*)d_in[2];
  const float* Wv   = (const float*)d_in[3];
  const float* Wp   = (const float*)d_in[4];
  const float* lamp = (const float*)d_in[5];
  const float* lsig = (const float*)d_in[6];
  float* out = (float*)d_out;

  char* ws = (char*)d_ws;
  const size_t NE = (size_t)BBATCH * NSEQ * DMODEL;  // 3,145,728
  short* xh = (short*)ws;            // later reused as attention output (bf16)
  short* WH = xh + NE;
  short* WL = WH + 4 * (size_t)WN;
  short* qs = WL + 4 * (size_t)WN;
  short* ks = qs + NE;
  short* vt = ks + NE;
  short* aoh = xh;                   // alias: x no longer needed after QKV

  prep_split<<<3648, 256, 0, stream>>>(x, Wq, Wk, Wv, Wp, xh, WH, WL);

  dim3 gq(64, 3, 3);
  gemm_mfma<0><<<gq, 256, 0, stream>>>(xh, WH, WL, lamp, qs, ks, vt, nullptr);

  attn_tile<<<dim3(8, 48), 512, 0, stream>>>(qs, ks, vt, aoh, lamp, lsig);

  dim3 gp(64, 3);
  gemm_mfma<1><<<gp, 256, 0, stream>>>(aoh, WH, WL, lamp, nullptr, nullptr, nullptr, out);
}

// Round 9
// 144.855 us; speedup vs baseline: 3.1124x; 1.2701x over previous
//
#include <hip/hip_runtime.h>
#include <hip/hip_bf16.h>
#include <math.h>

#define NUM_HEADS 6
#define DH 64
#define NSEQ 1024
#define DMODEL 384
#define BBATCH 8
#define WN 147456

typedef __attribute__((ext_vector_type(8))) short short8;
typedef __attribute__((ext_vector_type(4))) short s4v;
typedef __attribute__((ext_vector_type(4))) float floatx4;

static __device__ __forceinline__ short f2bf(float x) {
  union { float f; unsigned u; } un; un.f = x;
  unsigned r = un.u + 0x7fffu + ((un.u >> 16) & 1u);
  return (short)(r >> 16);
}
static __device__ __forceinline__ float bf2f(short s) {
  union { float f; unsigned u; } un;
  un.u = ((unsigned)(unsigned short)s) << 16;
  return un.f;
}

// ---------------- prep: x -> bf16, W -> bf16 hi/lo ----------------
__global__ __launch_bounds__(256) void prep_split(
    const float* __restrict__ x, const float* __restrict__ Wq,
    const float* __restrict__ Wk, const float* __restrict__ Wv,
    const float* __restrict__ Wp, short* __restrict__ xh,
    short* __restrict__ WH, short* __restrict__ WL) {
  const int idx = blockIdx.x * 256 + threadIdx.x;
  if (idx < 786432) {
    float4 v = ((const float4*)x)[idx];
    s4v h;
    h[0] = f2bf(v.x); h[1] = f2bf(v.y); h[2] = f2bf(v.z); h[3] = f2bf(v.w);
    ((s4v*)xh)[idx] = h;
  } else {
    int t = idx - 786432;
    int w = t / 36864;
    int rr = t - w * 36864;
    const float* W = (w == 0) ? Wq : (w == 1) ? Wk : (w == 2) ? Wv : Wp;
    float4 v = ((const float4*)W)[rr];
    s4v h, l;
    h[0] = f2bf(v.x); l[0] = f2bf(v.x - bf2f(h[0]));
    h[1] = f2bf(v.y); l[1] = f2bf(v.y - bf2f(h[1]));
    h[2] = f2bf(v.z); l[2] = f2bf(v.z - bf2f(h[2]));
    h[3] = f2bf(v.w); l[3] = f2bf(v.w - bf2f(h[3]));
    ((s4v*)(WH + (size_t)w * WN))[rr] = h;
    ((s4v*)(WL + (size_t)w * WN))[rr] = l;
  }
}

// ---------------- MFMA NT GEMM: C = A @ W^T, 2-pass, double-buffered ----------------
// FULLY UNROLLED pipeline (required: ar[cur] is a register array; un-unrolled
// it spills to scratch -> 257us/dispatch). One barrier per k-iter; DMA(k+1)
// + A-prefetch(k+1) issued right after it, in flight across compute(k).
template <int MODE>
__global__ __launch_bounds__(256) void gemm_mfma(
    const short* __restrict__ Abf, const short* __restrict__ WH,
    const short* __restrict__ WL, const float* __restrict__ lam_ptr,
    short* __restrict__ qs, short* __restrict__ ks, short* __restrict__ vt,
    float* __restrict__ outp) {
  __shared__ short sBh[2][4096], sBl[2][4096];

  const int tid = threadIdx.x;
  const int wave = tid >> 6;
  const int lane = tid & 63;
  const int quad = lane >> 4;
  const int l16 = lane & 15;

  const int bm = blockIdx.x * 128;
  const int bn = blockIdx.y * 128;
  const int z = (MODE == 0) ? blockIdx.z : 3;

  float cs = 1.0f;
  if (MODE == 0 && z == 0) cs = 0.125f / (1.0f + __expf(-lam_ptr[0]));

  const short* __restrict__ Wsel = ((wave < 2) ? WH : WL) + (size_t)z * WN;
  short* sBbase = (wave < 2) ? &sBh[0][0] : &sBl[0][0];
  const int Gb = (wave & 1) * 256;
  const short* srcp[4];
  int dsto[4];
#pragma unroll
  for (int i = 0; i < 4; ++i) {
    const int G = Gb + i * 64 + lane;
    const int row = G >> 2;
    const int g = (G & 3) ^ ((G >> 3) & 3);
    srcp[i] = Wsel + (size_t)(bn + row) * DMODEL + g * 8;
    dsto[i] = (Gb + i * 64) * 8;
  }

  const short* aptr[2];
#pragma unroll
  for (int mt = 0; mt < 2; ++mt)
    aptr[mt] = Abf + (size_t)(bm + wave * 32 + mt * 16 + l16) * DMODEL + quad * 8;

  floatx4 acc[2][8];
#pragma unroll
  for (int i = 0; i < 2; ++i)
#pragma unroll
    for (int j = 0; j < 8; ++j) acc[i][j] = (floatx4){0.f, 0.f, 0.f, 0.f};

#pragma unroll
  for (int i = 0; i < 4; ++i)
    __builtin_amdgcn_global_load_lds(
        (const __attribute__((address_space(1))) unsigned*)srcp[i],
        (__attribute__((address_space(3))) unsigned*)(sBbase + dsto[i]), 16, 0, 0);
  short8 ar[2][2];
  ar[0][0] = *(const short8*)aptr[0];
  ar[0][1] = *(const short8*)aptr[1];

#pragma unroll
  for (int it = 0; it < 12; ++it) {
    const int cur = it & 1, nxt = cur ^ 1;
    __syncthreads();  // DMA(it) landed; buf[nxt] readers (iter it-1) done
    if (it + 1 < 12) {
      const int ko = (it + 1) * 32;
#pragma unroll
      for (int i = 0; i < 4; ++i)
        __builtin_amdgcn_global_load_lds(
            (const __attribute__((address_space(1))) unsigned*)(srcp[i] + ko),
            (__attribute__((address_space(3))) unsigned*)(sBbase + nxt * 4096 + dsto[i]),
            16, 0, 0);
      ar[nxt][0] = *(const short8*)(aptr[0] + ko);
      ar[nxt][1] = *(const short8*)(aptr[1] + ko);
    }
#pragma unroll
    for (int nt = 0; nt < 8; ++nt) {
      const int row = nt * 16 + l16;
      const int off = row * 32 + ((quad ^ ((row >> 1) & 3)) << 3);
      short8 bfh = *(const short8*)&sBh[cur][off];
      short8 bfl = *(const short8*)&sBl[cur][off];
      acc[0][nt] = __builtin_amdgcn_mfma_f32_16x16x32_bf16(ar[cur][0], bfh, acc[0][nt], 0, 0, 0);
      acc[0][nt] = __builtin_amdgcn_mfma_f32_16x16x32_bf16(ar[cur][0], bfl, acc[0][nt], 0, 0, 0);
      acc[1][nt] = __builtin_amdgcn_mfma_f32_16x16x32_bf16(ar[cur][1], bfh, acc[1][nt], 0, 0, 0);
      acc[1][nt] = __builtin_amdgcn_mfma_f32_16x16x32_bf16(ar[cur][1], bfl, acc[1][nt], 0, 0, 0);
    }
  }

#pragma unroll
  for (int mt = 0; mt < 2; ++mt) {
    const int m0 = bm + wave * 32 + mt * 16 + quad * 4;
    const int b = m0 >> 10;
    const int n0 = m0 & (NSEQ - 1);
#pragma unroll
    for (int nt = 0; nt < 8; ++nt) {
      const int c = bn + nt * 16 + l16;
      if constexpr (MODE == 0) {
        const int head = c >> 6;
        const int d = c & 63;
        if (z == 2) {
          s4v sv;
          sv[0] = f2bf(acc[mt][nt][0]); sv[1] = f2bf(acc[mt][nt][1]);
          sv[2] = f2bf(acc[mt][nt][2]); sv[3] = f2bf(acc[mt][nt][3]);
          *(s4v*)&vt[((size_t)(b * NUM_HEADS + head) * DH + d) * NSEQ + n0] = sv;
        } else {
          short* tgt = z ? ks : qs;
#pragma unroll
          for (int r = 0; r < 4; ++r)
            tgt[((size_t)(b * NUM_HEADS + head) * NSEQ + n0 + r) * DH + d] =
                f2bf(acc[mt][nt][r] * cs);
        }
      } else {
#pragma unroll
        for (int r = 0; r < 4; ++r)
          outp[(size_t)(m0 + r) * DMODEL + c] = acc[mt][nt][r];
      }
    }
  }
}

// ---------------- LDS-shared tiled attention (R6 form: runtime chunk loop; the
// buf index only feeds LDS addressing, so no unroll needed -- full unroll
// regressed 38->72us via VGPR/I-cache bloat) ----------------
__global__ __launch_bounds__(512) void attn_tile(
    const short* __restrict__ qs, const short* __restrict__ ks,
    const short* __restrict__ vt, short* __restrict__ aoh,
    const float* __restrict__ lam_ptr, const float* __restrict__ lsig_ptr) {
  __shared__ short sK[2][4096];
  __shared__ short sVT[2][4096];
  __shared__ short sP[8 * 1024];

  const int tid = threadIdx.x;
  const int wave = tid >> 6;
  const int lane = tid & 63;
  const int quad = lane >> 4;
  const int l16 = lane & 15;
  const int l16a7 = l16 & 7;

  const int bh = blockIdx.y;
  const int qbase = blockIdx.x << 7;

  const short* qb = qs + (size_t)bh * NSEQ * DH;
  const short* kb = ks + (size_t)bh * NSEQ * DH;
  const short* vb = vt + (size_t)bh * DH * NSEQ;

  const float lam = 1.0f / (1.0f + __expf(-lam_ptr[0]));
  const float sg = log1pf(__expf(lsig_ptr[0])) + 1e-6f;
  const float ninv2s2 = -1.0f / (2.0f * sg * sg);
  const float pscale = 1.0f - lam;

  const int la31 = lane & 31;
  const float Etv = __expf(ninv2s2 * (float)(la31 * la31));
  float Exh[2][4];
#pragma unroll
  for (int mp = 0; mp < 2; ++mp)
#pragma unroll
    for (int r = 0; r < 4; ++r) {
      const int dx = (wave & 1) * 16 + l16 - mp * 16 - quad * 4 - r;
      const int idx = dx < 0 ? -dx : dx;
      Exh[mp][r] = __int_as_float(
          __builtin_amdgcn_ds_bpermute(idx << 2, __float_as_int(Etv)));
    }
  const int qy = (qbase >> 5) + (wave >> 1);

  const int qrow = qbase + wave * 16 + l16;
  short8 aqf0 = *(const short8*)&qb[(size_t)qrow * DH + quad * 8];
  short8 aqf1 = *(const short8*)&qb[(size_t)qrow * DH + 32 + quad * 8];

  const int Gr = tid >> 3;
  const int Gg = (tid & 7) ^ (Gr & 7);
  const short* srcK = kb + (size_t)Gr * DH + Gg * 8;
  const short* srcV = vb + (size_t)Gr * NSEQ + Gg * 8;
  const int dstoff = wave * 512;

  floatx4 oacc[4];
#pragma unroll
  for (int t = 0; t < 4; ++t) oacc[t] = (floatx4){0.f, 0.f, 0.f, 0.f};
  float plsum = 0.f;

  __builtin_amdgcn_global_load_lds(
      (const __attribute__((address_space(1))) unsigned*)srcK,
      (__attribute__((address_space(3))) unsigned*)&sK[0][dstoff], 16, 0, 0);
  __builtin_amdgcn_global_load_lds(
      (const __attribute__((address_space(1))) unsigned*)srcV,
      (__attribute__((address_space(3))) unsigned*)&sVT[0][dstoff], 16, 0, 0);

  for (int ch = 0; ch < 16; ++ch) {
    __syncthreads();
    if (ch + 1 < 16) {
      const int nb = (ch + 1) & 1;
      __builtin_amdgcn_global_load_lds(
          (const __attribute__((address_space(1))) unsigned*)(srcK + (ch + 1) * 4096),
          (__attribute__((address_space(3))) unsigned*)&sK[nb][dstoff], 16, 0, 0);
      __builtin_amdgcn_global_load_lds(
          (const __attribute__((address_space(1))) unsigned*)(srcV + (ch + 1) * 64),
          (__attribute__((address_space(3))) unsigned*)&sVT[nb][dstoff], 16, 0, 0);
    }
    const int buf = ch & 1;

    short8 kf[4][2];
#pragma unroll
    for (int mt = 0; mt < 4; ++mt) {
      const int row = mt * 16 + l16;
#pragma unroll
      for (int h = 0; h < 2; ++h) {
        const int g = h * 4 + quad;
        kf[mt][h] = *(const short8*)&sK[buf][row * 64 + ((g ^ (row & 7)) << 3)];
      }
    }

    floatx4 S[4];
#pragma unroll
    for (int mt = 0; mt < 4; ++mt) {
      floatx4 c = {0.f, 0.f, 0.f, 0.f};
      c = __builtin_amdgcn_mfma_f32_16x16x32_bf16(kf[mt][0], aqf0, c, 0, 0, 0);
      c = __builtin_amdgcn_mfma_f32_16x16x32_bf16(kf[mt][1], aqf1, c, 0, 0, 0);
      S[mt] = c;
    }

    const float dy0 = (float)(qy - 2 * ch);
    const float dy1 = dy0 - 1.0f;
    float ey[2];
    ey[0] = pscale * __expf(ninv2s2 * dy0 * dy0);
    ey[1] = pscale * __expf(ninv2s2 * dy1 * dy1);

#pragma unroll
    for (int mt = 0; mt < 4; ++mt) {
      s4v pk;
#pragma unroll
      for (int r = 0; r < 4; ++r) {
        const float p = __expf(fmaf(ey[mt >> 1], Exh[mt & 1][r], S[mt][r]));
        plsum += p;
        pk[r] = f2bf(p);
      }
      const int gg = mt * 4 + quad;
      const int off = wave * 1024 + l16 * 64 + (((gg >> 1) ^ l16a7) << 3) + ((gg & 1) << 2);
      *(s4v*)&sP[off] = pk;
    }

    short8 pA0 = *(const short8*)&sP[wave * 1024 + l16 * 64 + ((quad ^ l16a7) << 3)];
    short8 pA1 = *(const short8*)&sP[wave * 1024 + l16 * 64 + (((4 + quad) ^ l16a7) << 3)];

#pragma unroll
    for (int dt = 0; dt < 4; ++dt) {
      const int row = dt * 16 + l16;
      short8 vf0 = *(const short8*)&sVT[buf][row * 64 + ((quad ^ (row & 7)) << 3)];
      short8 vf1 = *(const short8*)&sVT[buf][row * 64 + (((4 + quad) ^ (row & 7)) << 3)];
      oacc[dt] = __builtin_amdgcn_mfma_f32_16x16x32_bf16(pA0, vf0, oacc[dt], 0, 0, 0);
      oacc[dt] = __builtin_amdgcn_mfma_f32_16x16x32_bf16(pA1, vf1, oacc[dt], 0, 0, 0);
    }
  }

  plsum += __shfl_xor(plsum, 16, 64);
  plsum += __shfl_xor(plsum, 32, 64);
  const float inv = 1.0f / plsum;
  float invr[4];
#pragma unroll
  for (int rr = 0; rr < 4; ++rr)
    invr[rr] = __int_as_float(
        __builtin_amdgcn_ds_bpermute((quad * 4 + rr) << 2, __float_as_int(inv)));

  const int b = bh / NUM_HEADS, head = bh % NUM_HEADS;
#pragma unroll
  for (int dt = 0; dt < 4; ++dt)
#pragma unroll
    for (int rr = 0; rr < 4; ++rr)
      aoh[(size_t)(b * NSEQ + qbase + wave * 16 + quad * 4 + rr) * DMODEL +
          head * DH + dt * 16 + l16] = f2bf(oacc[dt][rr] * invr[rr]);
}

extern "C" void kernel_launch(void* const* d_in, const int* in_sizes, int n_in,
                              void* d_out, int out_size, void* d_ws, size_t ws_size,
                              hipStream_t stream) {
  const float* x    = (const float*)d_in[0];
  const float* Wq   = (const float*)d_in[1];
  const float* Wk   = (const float*)d_in[2];
  const float* Wv   = (const float*)d_in[3];
  const float* Wp   = (const float*)d_in[4];
  const float* lamp = (const float*)d_in[5];
  const float* lsig = (const float*)d_in[6];
  float* out = (float*)d_out;

  char* ws = (char*)d_ws;
  const size_t NE = (size_t)BBATCH * NSEQ * DMODEL;  // 3,145,728
  short* xh = (short*)ws;            // later reused as attention output (bf16)
  short* WH = xh + NE;
  short* WL = WH + 4 * (size_t)WN;
  short* qs = WL + 4 * (size_t)WN;
  short* ks = qs + NE;
  short* vt = ks + NE;
  short* aoh = xh;                   // alias: x no longer needed after QKV

  prep_split<<<3648, 256, 0, stream>>>(x, Wq, Wk, Wv, Wp, xh, WH, WL);

  dim3 gq(64, 3, 3);
  gemm_mfma<0><<<gq, 256, 0, stream>>>(xh, WH, WL, lamp, qs, ks, vt, nullptr);

  attn_tile<<<dim3(8, 48), 512, 0, stream>>>(qs, ks, vt, aoh, lamp, lsig);

  dim3 gp(64, 3);
  gemm_mfma<1><<<gp, 256, 0, stream>>>(aoh, WH, WL, lamp, nullptr, nullptr, nullptr, out);
}

// Round 10
// 135.300 us; speedup vs baseline: 3.3322x; 1.0706x over previous
//
#include <hip/hip_runtime.h>
#include <hip/hip_bf16.h>
#include <hip/hip_fp16.h>
#include <math.h>

#define NUM_HEADS 6
#define DH 64
#define NSEQ 1024
#define DMODEL 384
#define BBATCH 8
#define WN 147456

typedef __attribute__((ext_vector_type(8))) _Float16 half8;
typedef __attribute__((ext_vector_type(4))) _Float16 half4v;
typedef __attribute__((ext_vector_type(4))) float floatx4;

// ---------------- prep: x, W -> fp16 ----------------
__global__ __launch_bounds__(256) void prep_f16(
    const float* __restrict__ x, const float* __restrict__ Wq,
    const float* __restrict__ Wk, const float* __restrict__ Wv,
    const float* __restrict__ Wp, _Float16* __restrict__ xh,
    _Float16* __restrict__ WH) {
  const int idx = blockIdx.x * 256 + threadIdx.x;
  if (idx < 786432) {
    float4 v = ((const float4*)x)[idx];
    half4v h;
    h[0] = (_Float16)v.x; h[1] = (_Float16)v.y;
    h[2] = (_Float16)v.z; h[3] = (_Float16)v.w;
    ((half4v*)xh)[idx] = h;
  } else {
    int t = idx - 786432;
    int w = t / 36864;
    int rr = t - w * 36864;
    const float* W = (w == 0) ? Wq : (w == 1) ? Wk : (w == 2) ? Wv : Wp;
    float4 v = ((const float4*)W)[rr];
    half4v h;
    h[0] = (_Float16)v.x; h[1] = (_Float16)v.y;
    h[2] = (_Float16)v.z; h[3] = (_Float16)v.w;
    ((half4v*)(WH + (size_t)w * WN))[rr] = h;
  }
}

// ---------------- MFMA NT GEMM: C = A @ W^T, fp16 single-pass ----------------
// BK=64, 6 fully-unrolled double-buffered iters (unroll REQUIRED: ar[cur] is a
// register array; runtime-indexed it spills to scratch -> 257us, R7 lesson).
// W tile 128x64 fp16 (16KB) x2 bufs staged via global_load_lds w16; swizzle:
// row r, 16B-granule g at r*64 + ((g^(r&7))<<3) halves. A direct global b128.
template <int MODE>
__global__ __launch_bounds__(256) void gemm_f16(
    const _Float16* __restrict__ Abf, const _Float16* __restrict__ WH,
    const float* __restrict__ lam_ptr,
    _Float16* __restrict__ qs, _Float16* __restrict__ ks,
    _Float16* __restrict__ vt, float* __restrict__ outp) {
  __shared__ _Float16 sB[2][8192];

  const int tid = threadIdx.x;
  const int wave = tid >> 6;
  const int lane = tid & 63;
  const int quad = lane >> 4;
  const int l16 = lane & 15;

  const int bm = blockIdx.x * 128;
  const int bn = blockIdx.y * 128;
  const int z = (MODE == 0) ? blockIdx.z : 3;

  float cs = 1.0f;
  if (MODE == 0 && z == 0) cs = 0.125f / (1.0f + __expf(-lam_ptr[0]));

  const _Float16* __restrict__ Wsel = WH + (size_t)z * WN;
  // staging: granule Gd = i*256 + tid; row=Gd>>3, slot=Gd&7, src g=slot^(row&7)
  const _Float16* srcp[4];
  int dsto[4];
#pragma unroll
  for (int i = 0; i < 4; ++i) {
    const int Gd = i * 256 + tid;
    const int row = Gd >> 3;
    const int g = (Gd & 7) ^ (row & 7);
    srcp[i] = Wsel + (size_t)(bn + row) * DMODEL + g * 8;
    dsto[i] = (i * 256 + wave * 64) * 8;  // + HW lane*16B
  }

  const _Float16* aptr[2];
#pragma unroll
  for (int mt = 0; mt < 2; ++mt)
    aptr[mt] = Abf + (size_t)(bm + wave * 32 + mt * 16 + l16) * DMODEL + quad * 8;

  floatx4 acc[2][8];
#pragma unroll
  for (int i = 0; i < 2; ++i)
#pragma unroll
    for (int j = 0; j < 8; ++j) acc[i][j] = (floatx4){0.f, 0.f, 0.f, 0.f};

#pragma unroll
  for (int i = 0; i < 4; ++i)
    __builtin_amdgcn_global_load_lds(
        (const __attribute__((address_space(1))) unsigned*)srcp[i],
        (__attribute__((address_space(3))) unsigned*)(&sB[0][0] + dsto[i]), 16, 0, 0);
  half8 ar[2][2][2];
  ar[0][0][0] = *(const half8*)(aptr[0]);
  ar[0][0][1] = *(const half8*)(aptr[0] + 32);
  ar[0][1][0] = *(const half8*)(aptr[1]);
  ar[0][1][1] = *(const half8*)(aptr[1] + 32);

#pragma unroll
  for (int it = 0; it < 6; ++it) {
    const int cur = it & 1, nxt = cur ^ 1;
    __syncthreads();  // DMA(it) landed; buf[nxt] readers (it-1) done
    if (it + 1 < 6) {
      const int ko = (it + 1) * 64;
#pragma unroll
      for (int i = 0; i < 4; ++i)
        __builtin_amdgcn_global_load_lds(
            (const __attribute__((address_space(1))) unsigned*)(srcp[i] + ko),
            (__attribute__((address_space(3))) unsigned*)(&sB[nxt][0] + dsto[i]),
            16, 0, 0);
      ar[nxt][0][0] = *(const half8*)(aptr[0] + ko);
      ar[nxt][0][1] = *(const half8*)(aptr[0] + ko + 32);
      ar[nxt][1][0] = *(const half8*)(aptr[1] + ko);
      ar[nxt][1][1] = *(const half8*)(aptr[1] + ko + 32);
    }
#pragma unroll
    for (int nt = 0; nt < 8; ++nt) {
      const int row = nt * 16 + l16;
      half8 bf0 = *(const half8*)&sB[cur][row * 64 + ((quad ^ (row & 7)) << 3)];
      half8 bf1 = *(const half8*)&sB[cur][row * 64 + (((4 + quad) ^ (row & 7)) << 3)];
      acc[0][nt] = __builtin_amdgcn_mfma_f32_16x16x32_f16(ar[cur][0][0], bf0, acc[0][nt], 0, 0, 0);
      acc[0][nt] = __builtin_amdgcn_mfma_f32_16x16x32_f16(ar[cur][0][1], bf1, acc[0][nt], 0, 0, 0);
      acc[1][nt] = __builtin_amdgcn_mfma_f32_16x16x32_f16(ar[cur][1][0], bf0, acc[1][nt], 0, 0, 0);
      acc[1][nt] = __builtin_amdgcn_mfma_f32_16x16x32_f16(ar[cur][1][1], bf1, acc[1][nt], 0, 0, 0);
    }
  }

#pragma unroll
  for (int mt = 0; mt < 2; ++mt) {
    const int m0 = bm + wave * 32 + mt * 16 + quad * 4;
    const int b = m0 >> 10;
    const int n0 = m0 & (NSEQ - 1);
#pragma unroll
    for (int nt = 0; nt < 8; ++nt) {
      const int c = bn + nt * 16 + l16;
      if constexpr (MODE == 0) {
        const int head = c >> 6;
        const int d = c & 63;
        if (z == 2) {
          half4v sv;
          sv[0] = (_Float16)acc[mt][nt][0]; sv[1] = (_Float16)acc[mt][nt][1];
          sv[2] = (_Float16)acc[mt][nt][2]; sv[3] = (_Float16)acc[mt][nt][3];
          *(half4v*)&vt[((size_t)(b * NUM_HEADS + head) * DH + d) * NSEQ + n0] = sv;
        } else {
          _Float16* tgt = z ? ks : qs;
#pragma unroll
          for (int r = 0; r < 4; ++r)
            tgt[((size_t)(b * NUM_HEADS + head) * NSEQ + n0 + r) * DH + d] =
                (_Float16)(acc[mt][nt][r] * cs);
        }
      } else {
#pragma unroll
        for (int r = 0; r < 4; ++r)
          outp[(size_t)(m0 + r) * DMODEL + c] = acc[mt][nt][r];
      }
    }
  }
}

// ---------------- LDS-shared tiled attention, fp16 ----------------
// Grid (48 bh, 8 qtile): linear id = bh + 48*qtile => all 8 q-blocks of one
// bh share id%8 => same XCD (round-robin heuristic) => K/V L2-resident
// (6 bh x 256KB = 1.5MB < 4MB XCD L2). Runtime chunk loop (buf only feeds
// LDS addressing; full unroll regressed 38->72us, R8 lesson).
__global__ __launch_bounds__(512) void attn_tile(
    const _Float16* __restrict__ qs, const _Float16* __restrict__ ks,
    const _Float16* __restrict__ vt, _Float16* __restrict__ aoh,
    const float* __restrict__ lam_ptr, const float* __restrict__ lsig_ptr) {
  __shared__ _Float16 sK[2][4096];
  __shared__ _Float16 sVT[2][4096];
  __shared__ _Float16 sP[8 * 1024];

  const int tid = threadIdx.x;
  const int wave = tid >> 6;
  const int lane = tid & 63;
  const int quad = lane >> 4;
  const int l16 = lane & 15;
  const int l16a7 = l16 & 7;

  const int bh = blockIdx.x;
  const int qbase = blockIdx.y << 7;

  const _Float16* qb = qs + (size_t)bh * NSEQ * DH;
  const _Float16* kb = ks + (size_t)bh * NSEQ * DH;
  const _Float16* vb = vt + (size_t)bh * DH * NSEQ;

  const float lam = 1.0f / (1.0f + __expf(-lam_ptr[0]));
  const float sg = log1pf(__expf(lsig_ptr[0])) + 1e-6f;
  const float ninv2s2 = -1.0f / (2.0f * sg * sg);
  const float pscale = 1.0f - lam;

  const int la31 = lane & 31;
  const float Etv = __expf(ninv2s2 * (float)(la31 * la31));
  float Exh[2][4];
#pragma unroll
  for (int mp = 0; mp < 2; ++mp)
#pragma unroll
    for (int r = 0; r < 4; ++r) {
      const int dx = (wave & 1) * 16 + l16 - mp * 16 - quad * 4 - r;
      const int idx = dx < 0 ? -dx : dx;
      Exh[mp][r] = __int_as_float(
          __builtin_amdgcn_ds_bpermute(idx << 2, __float_as_int(Etv)));
    }
  const int qy = (qbase >> 5) + (wave >> 1);

  const int qrow = qbase + wave * 16 + l16;
  half8 aqf0 = *(const half8*)&qb[(size_t)qrow * DH + quad * 8];
  half8 aqf1 = *(const half8*)&qb[(size_t)qrow * DH + 32 + quad * 8];

  const int Gr = tid >> 3;
  const int Gg = (tid & 7) ^ (Gr & 7);
  const _Float16* srcK = kb + (size_t)Gr * DH + Gg * 8;
  const _Float16* srcV = vb + (size_t)Gr * NSEQ + Gg * 8;
  const int dstoff = wave * 512;

  floatx4 oacc[4];
#pragma unroll
  for (int t = 0; t < 4; ++t) oacc[t] = (floatx4){0.f, 0.f, 0.f, 0.f};
  float plsum = 0.f;

  __builtin_amdgcn_global_load_lds(
      (const __attribute__((address_space(1))) unsigned*)srcK,
      (__attribute__((address_space(3))) unsigned*)&sK[0][dstoff], 16, 0, 0);
  __builtin_amdgcn_global_load_lds(
      (const __attribute__((address_space(1))) unsigned*)srcV,
      (__attribute__((address_space(3))) unsigned*)&sVT[0][dstoff], 16, 0, 0);

  for (int ch = 0; ch < 16; ++ch) {
    __syncthreads();
    if (ch + 1 < 16) {
      const int nb = (ch + 1) & 1;
      __builtin_amdgcn_global_load_lds(
          (const __attribute__((address_space(1))) unsigned*)(srcK + (ch + 1) * 4096),
          (__attribute__((address_space(3))) unsigned*)&sK[nb][dstoff], 16, 0, 0);
      __builtin_amdgcn_global_load_lds(
          (const __attribute__((address_space(1))) unsigned*)(srcV + (ch + 1) * 64),
          (__attribute__((address_space(3))) unsigned*)&sVT[nb][dstoff], 16, 0, 0);
    }
    const int buf = ch & 1;

    half8 kf[4][2];
#pragma unroll
    for (int mt = 0; mt < 4; ++mt) {
      const int row = mt * 16 + l16;
#pragma unroll
      for (int h = 0; h < 2; ++h) {
        const int g = h * 4 + quad;
        kf[mt][h] = *(const half8*)&sK[buf][row * 64 + ((g ^ (row & 7)) << 3)];
      }
    }

    floatx4 S[4];
#pragma unroll
    for (int mt = 0; mt < 4; ++mt) {
      floatx4 c = {0.f, 0.f, 0.f, 0.f};
      c = __builtin_amdgcn_mfma_f32_16x16x32_f16(kf[mt][0], aqf0, c, 0, 0, 0);
      c = __builtin_amdgcn_mfma_f32_16x16x32_f16(kf[mt][1], aqf1, c, 0, 0, 0);
      S[mt] = c;
    }

    const float dy0 = (float)(qy - 2 * ch);
    const float dy1 = dy0 - 1.0f;
    float ey[2];
    ey[0] = pscale * __expf(ninv2s2 * dy0 * dy0);
    ey[1] = pscale * __expf(ninv2s2 * dy1 * dy1);

#pragma unroll
    for (int mt = 0; mt < 4; ++mt) {
      half4v pk;
#pragma unroll
      for (int r = 0; r < 4; ++r) {
        const float p = __expf(fmaf(ey[mt >> 1], Exh[mt & 1][r], S[mt][r]));
        plsum += p;
        pk[r] = (_Float16)p;
      }
      const int gg = mt * 4 + quad;
      const int off = wave * 1024 + l16 * 64 + (((gg >> 1) ^ l16a7) << 3) + ((gg & 1) << 2);
      *(half4v*)&sP[off] = pk;
    }

    half8 pA0 = *(const half8*)&sP[wave * 1024 + l16 * 64 + ((quad ^ l16a7) << 3)];
    half8 pA1 = *(const half8*)&sP[wave * 1024 + l16 * 64 + (((4 + quad) ^ l16a7) << 3)];

#pragma unroll
    for (int dt = 0; dt < 4; ++dt) {
      const int row = dt * 16 + l16;
      half8 vf0 = *(const half8*)&sVT[buf][row * 64 + ((quad ^ (row & 7)) << 3)];
      half8 vf1 = *(const half8*)&sVT[buf][row * 64 + (((4 + quad) ^ (row & 7)) << 3)];
      oacc[dt] = __builtin_amdgcn_mfma_f32_16x16x32_f16(pA0, vf0, oacc[dt], 0, 0, 0);
      oacc[dt] = __builtin_amdgcn_mfma_f32_16x16x32_f16(pA1, vf1, oacc[dt], 0, 0, 0);
    }
  }

  plsum += __shfl_xor(plsum, 16, 64);
  plsum += __shfl_xor(plsum, 32, 64);
  const float inv = 1.0f / plsum;
  float invr[4];
#pragma unroll
  for (int rr = 0; rr < 4; ++rr)
    invr[rr] = __int_as_float(
        __builtin_amdgcn_ds_bpermute((quad * 4 + rr) << 2, __float_as_int(inv)));

  const int b = bh / NUM_HEADS, head = bh % NUM_HEADS;
#pragma unroll
  for (int dt = 0; dt < 4; ++dt)
#pragma unroll
    for (int rr = 0; rr < 4; ++rr)
      aoh[(size_t)(b * NSEQ + qbase + wave * 16 + quad * 4 + rr) * DMODEL +
          head * DH + dt * 16 + l16] = (_Float16)(oacc[dt][rr] * invr[rr]);
}

extern "C" void kernel_launch(void* const* d_in, const int* in_sizes, int n_in,
                              void* d_out, int out_size, void* d_ws, size_t ws_size,
                              hipStream_t stream) {
  const float* x    = (const float*)d_in[0];
  const float* Wq   = (const float*)d_in[1];
  const float* Wk   = (const float*)d_in[2];
  const float* Wv   = (const float*)d_in[3];
  const float* Wp   = (const float*)d_in[4];
  const float* lamp = (const float*)d_in[5];
  const float* lsig = (const float*)d_in[6];
  float* out = (float*)d_out;

  char* ws = (char*)d_ws;
  const size_t NE = (size_t)BBATCH * NSEQ * DMODEL;  // 3,145,728
  _Float16* xh = (_Float16*)ws;      // later reused as attention output
  _Float16* WH = xh + NE;
  _Float16* qs = WH + 4 * (size_t)WN;
  _Float16* ks = qs + NE;
  _Float16* vt = ks + NE;
  _Float16* aoh = xh;                // alias: x no longer needed after QKV

  prep_f16<<<3648, 256, 0, stream>>>(x, Wq, Wk, Wv, Wp, xh, WH);

  dim3 gq(64, 3, 3);
  gemm_f16<0><<<gq, 256, 0, stream>>>(xh, WH, lamp, qs, ks, vt, nullptr);

  attn_tile<<<dim3(48, 8), 512, 0, stream>>>(qs, ks, vt, aoh, lamp, lsig);

  dim3 gp(64, 3);
  gemm_f16<1><<<gp, 256, 0, stream>>>(aoh, WH, lamp, nullptr, nullptr, nullptr, out);
}